// Round 6
// baseline (243.129 us; speedup 1.0000x reference)
//
#include <hip/hip_runtime.h>
#include <hip/hip_bf16.h>
#include <stdint.h>

typedef short short8 __attribute__((ext_vector_type(8)));
typedef float f32x4 __attribute__((ext_vector_type(4)));

// Problem constants
constexpr int SEQ   = 2048;   // T
constexpr int DM    = 1024;   // model dim
constexpr int NHEAD = 16;
constexpr int HD    = 64;     // head dim
constexpr int LDQ   = 1152;   // QKV row stride: 1024 Q | 64 K | 64 V
constexpr int BATCH = 2;
constexpr int KD    = 1024;   // GEMM K (both GEMMs): compile-time for imm offsets

__device__ __forceinline__ unsigned short f2bf(float f) {
    union { float f; uint32_t u; } v; v.f = f;
    uint32_t u = v.u;
    uint32_t r = (u + 0x7fffu + ((u >> 16) & 1u)) >> 16;
    return (unsigned short)r;
}

// async global->LDS, 16B per lane (attn staging only).
typedef __attribute__((address_space(1))) const void gvoid_t;
typedef __attribute__((address_space(3))) void lvoid_t;
__device__ __forceinline__ void gload16(const void* g, void* l) {
    __builtin_amdgcn_global_load_lds((gvoid_t*)g, (lvoid_t*)l, 16, 0, 0);
}

// ---------------- cast x (fp32 -> bf16), vectorized ----------------
__global__ __launch_bounds__(256) void cast_x_kernel(
        const float* __restrict__ x, unsigned short* __restrict__ xb, int n) {
    int i = (blockIdx.x * 256 + threadIdx.x) * 4;
    if (i >= n) return;
    const float4 v = *(const float4*)(x + i);
    ushort4 o;
    o.x = f2bf(v.x); o.y = f2bf(v.y); o.z = f2bf(v.z); o.w = f2bf(v.w);
    *(ushort4*)(xb + i) = o;
}

// ---- fused weight prep: cast+transpose Wq,Wk,Wv,Wo in one launch ----
__global__ __launch_bounds__(256) void prep_w_kernel(
        const float* __restrict__ Wq, const float* __restrict__ Wk,
        const float* __restrict__ Wv, const float* __restrict__ Wo,
        unsigned short* __restrict__ wtq, unsigned short* __restrict__ wot) {
    __shared__ unsigned short tile[32][33];
    int z = blockIdx.z;
    const float* W; unsigned short* Wt; int C;
    if (z == 0)      { W = Wq; Wt = wtq;                              C = DM; }
    else if (z == 1) { W = Wk; Wt = wtq + (size_t)DM * DM;            C = HD; }
    else if (z == 2) { W = Wv; Wt = wtq + (size_t)(DM + HD) * DM;     C = HD; }
    else             { W = Wo; Wt = wot;                              C = DM; }
    int c0 = blockIdx.x * 32, r0 = blockIdx.y * 32;
    if (c0 >= C) return;
    int tx = threadIdx.x & 31, ty = threadIdx.x >> 5;  // ty 0..7
    for (int i = ty; i < 32; i += 8)
        tile[i][tx] = f2bf(W[(size_t)(r0 + i) * C + (c0 + tx)]);
    __syncthreads();
    for (int i = ty; i < 32; i += 8)
        Wt[(size_t)(c0 + i) * DM + (r0 + tx)] = tile[tx][i];
}

// ------ GEMM, direct-to-register (NO LDS, NO barriers): C = A @ Bt^T ------
// R6 theory: 6 rounds of LDS-staged variants (64^2/128^2/128x64, drain-0 and
// counted-vmcnt) all pin non-attn at ~112-123 us (~175 TF, 40x above the
// pure-MFMA floor) -- the invariant is the per-K-step vmcnt(0)+barrier drain.
// Both operands are L2-resident (weights 2.3MB/XCD, x strip ~1MB/XCD with the
// XCD swizzle; HBM pct ~4). Common-mistake #7: don't LDS-stage what L2 serves.
// Here each wave owns a 64x32 tile (acc[4][2]) and loads its A/B fragments
// straight from global into VGPRs: per 32-K chunk 4 A + 2 B short8 loads +
// 8 MFMA, explicit 2-stage F0/F1 rotation (static indices, rule #20).
// KD=1024 compile-time + full unroll folds all k-offsets into the 13-bit
// global_load imm (0..2032B) -- zero per-iteration address VALU, and the
// compiler emits counted s_waitcnt (not drain-0) for plain loads.
// Fragment layouts identical to the proven LDS version (A-frag: row=ln,
// k=quad*8; C/D: row=quad*4+r, col=ln) -> epilogue indices unchanged.
// Block = 2x2 waves = 128x64 tile. Grid: QKV 576 (ncols=18), out 512 (16);
// bijective XCD remap, rows_per_xcd = 576/(8*18)=4 and 512/(8*16)=4.
__global__ __launch_bounds__(256) void gemm_direct_kernel(
        const unsigned short* __restrict__ A,
        const unsigned short* __restrict__ Bt,
        void* __restrict__ Cout,
        unsigned short* __restrict__ VtOut,
        int N, int out_bf16, int ncols) {
    int lane = threadIdx.x & 63, wave = threadIdx.x >> 6;
    int ln = lane & 15, quad = lane >> 4;
    int wm = wave >> 1, wn = wave & 1;

    // XCD-aware block remap (bijective: gridDim.x % 8 == 0)
    int g = blockIdx.x;
    int xcd = g & 7, idx = g >> 3;
    int rows_per_xcd = (int)(gridDim.x >> 3) / ncols;
    int row = xcd * rows_per_xcd + idx / ncols;
    int col = idx % ncols;
    int m0 = row * 128, n0 = col * 64;

    // per-lane fragment base pointers (k advances via immediate offsets)
    const unsigned short* aB0 = A + (size_t)(m0 + wm * 64 +  0 + ln) * KD + quad * 8;
    const unsigned short* aB1 = A + (size_t)(m0 + wm * 64 + 16 + ln) * KD + quad * 8;
    const unsigned short* aB2 = A + (size_t)(m0 + wm * 64 + 32 + ln) * KD + quad * 8;
    const unsigned short* aB3 = A + (size_t)(m0 + wm * 64 + 48 + ln) * KD + quad * 8;
    const unsigned short* bB0 = Bt + (size_t)(n0 + wn * 32 +  0 + ln) * KD + quad * 8;
    const unsigned short* bB1 = Bt + (size_t)(n0 + wn * 32 + 16 + ln) * KD + quad * 8;

    f32x4 acc[4][2];
#pragma unroll
    for (int i = 0; i < 4; ++i)
#pragma unroll
        for (int j = 0; j < 2; ++j) acc[i][j] = f32x4{0, 0, 0, 0};

    short8 a0[4], b0[2], a1[4], b1[2];
    // preload chunk 0
    a0[0] = *(const short8*)(aB0); a0[1] = *(const short8*)(aB1);
    a0[2] = *(const short8*)(aB2); a0[3] = *(const short8*)(aB3);
    b0[0] = *(const short8*)(bB0); b0[1] = *(const short8*)(bB1);

#pragma unroll
    for (int kk = 0; kk < KD; kk += 64) {
        // load chunk kk+32 into stage-1 while stage-0 computes
        a1[0] = *(const short8*)(aB0 + kk + 32); a1[1] = *(const short8*)(aB1 + kk + 32);
        a1[2] = *(const short8*)(aB2 + kk + 32); a1[3] = *(const short8*)(aB3 + kk + 32);
        b1[0] = *(const short8*)(bB0 + kk + 32); b1[1] = *(const short8*)(bB1 + kk + 32);
#pragma unroll
        for (int mt = 0; mt < 4; ++mt)
#pragma unroll
            for (int nt = 0; nt < 2; ++nt)
                acc[mt][nt] = __builtin_amdgcn_mfma_f32_16x16x32_bf16(
                    a0[mt], b0[nt], acc[mt][nt], 0, 0, 0);
        if (kk + 64 < KD) {   // load chunk kk+64 into stage-0
            a0[0] = *(const short8*)(aB0 + kk + 64); a0[1] = *(const short8*)(aB1 + kk + 64);
            a0[2] = *(const short8*)(aB2 + kk + 64); a0[3] = *(const short8*)(aB3 + kk + 64);
            b0[0] = *(const short8*)(bB0 + kk + 64); b0[1] = *(const short8*)(bB1 + kk + 64);
        }
#pragma unroll
        for (int mt = 0; mt < 4; ++mt)
#pragma unroll
            for (int nt = 0; nt < 2; ++nt)
                acc[mt][nt] = __builtin_amdgcn_mfma_f32_16x16x32_bf16(
                    a1[mt], b1[nt], acc[mt][nt], 0, 0, 0);
    }

    if (out_bf16) {
        unsigned short* C = (unsigned short*)Cout;
#pragma unroll
        for (int mt = 0; mt < 4; ++mt)
#pragma unroll
            for (int nt = 0; nt < 2; ++nt)
#pragma unroll
                for (int r = 0; r < 4; ++r) {
                    int rr = m0 + wm * 64 + mt * 16 + quad * 4 + r;
                    int cc = n0 + wn * 32 + nt * 16 + ln;
                    unsigned short hv = f2bf(acc[mt][nt][r]);
                    C[(size_t)rr * N + cc] = hv;
                    if (VtOut != nullptr && cc >= DM + HD) {  // V cols: also transposed
                        int d = cc - (DM + HD);               // 0..63
                        int bb = rr >> 11, s = rr & 2047;
                        VtOut[((size_t)bb * HD + d) * SEQ + s] = hv;
                    }
                }
    } else {
        float* C = (float*)Cout;
#pragma unroll
        for (int mt = 0; mt < 4; ++mt)
#pragma unroll
            for (int nt = 0; nt < 2; ++nt)
#pragma unroll
                for (int r = 0; r < 4; ++r) {
                    int rr = m0 + wm * 64 + mt * 16 + quad * 4 + r;
                    int cc = n0 + wn * 32 + nt * 16 + ln;
                    C[(size_t)rr * N + cc] = acc[mt][nt][r];
                }
    }
}

// ---------------- flash attention (multi-query, causal) ----------------
// R0 design restored verbatim (best measured: 51.4 us; every structural
// variant regressed: 8-wave 54.4, 2-barrier pipeline 60.5, 32-row 68.3).
// 64-key steps: block stages K(64x64) + Vt(64x64) into double-buffered LDS
// via global_load_lds ((row&7) xor chunk swizzle). 4 waves share the tiles;
// wave w owns q-tile jg*4+w: jg mask-free steps + 1 partial step. pbuf
// (per-wave 16x64, xor-swizzled) for the P C-layout -> A-layout round trip;
// LDS 40960 B = 4 blocks/CU. Constant-max streaming softmax; P truncation.
__global__ __launch_bounds__(256) void attn_kernel(
        const unsigned short* __restrict__ QKV,
        const unsigned short* __restrict__ Vt,
        unsigned short* __restrict__ Y) {
    __shared__ unsigned short ldsK[2][64 * 64];
    __shared__ unsigned short ldsV[2][64 * 64];
    __shared__ unsigned short pbuf[4][16 * 64];   // swizzled, per-wave

    int lane = threadIdx.x & 63, wave = threadIdx.x >> 6;
    int ln = lane & 15, quad = lane >> 4;
    int bid = blockIdx.x;
    int jg = 31 - (bid >> 5);             // heavy-first
    int bh = bid & 31;
    int h = bh & 15, b = bh >> 4;
    int q0 = (jg * 4 + wave) * 16;
    const size_t baseRow = (size_t)b * SEQ;
    const unsigned short* Vb = Vt + (size_t)b * HD * SEQ;

    int t = threadIdx.x;
    int trow = t >> 3, tcb = t & 7;
    int cbg = tcb ^ (trow & 7);
    const unsigned short* gK = QKV + (baseRow + trow) * LDQ + DM + cbg * 8;
    const unsigned short* gV = Vb + (size_t)trow * SEQ + cbg * 8;
    int dstoff = trow * 64 + tcb * 8;

    auto stageKV = [&](int s0n, int buf) {
#pragma unroll
        for (int rr = 0; rr < 2; ++rr) {
            gload16(gK + (size_t)(s0n + 32 * rr) * LDQ, &ldsK[buf][dstoff + rr * 2048]);
            gload16(gV + (size_t)32 * rr * SEQ + s0n,   &ldsV[buf][dstoff + rr * 2048]);
        }
    };

    // Q fragments (A-layout)
    short8 aQ0, aQ1;
    {
        const unsigned short* qp = QKV + (baseRow + q0 + ln) * LDQ + h * HD + quad * 8;
        aQ0 = *(const short8*)(qp);
        aQ1 = *(const short8*)(qp + 32);
    }

    float lsum[4] = {0.f, 0.f, 0.f, 0.f};
    f32x4 o[4];
    for (int nt = 0; nt < 4; ++nt) o[nt] = f32x4{0, 0, 0, 0};

    const float c_exp = 0.1803368802f;    // 0.125 * log2(e)
    unsigned short* pb = &pbuf[wave][0];

    auto computeStep = [&](int s0, int buf, bool partial) {
        const unsigned short* Kb = ldsK[buf];
        const unsigned short* Vf = ldsV[buf];
#pragma unroll
        for (int c = 0; c < 4; ++c) {
            int kbase = s0 + c * 16;
            if (partial && kbase > q0 + 15) {   // fully masked tile: zero P
#pragma unroll
                for (int r = 0; r < 4; ++r) {
                    int row = quad * 4 + r;
                    pb[row * 64 + (((c * 2 + (ln >> 3)) ^ (row & 7)) * 8) + (ln & 7)] = 0;
                }
                continue;
            }
            short8 k0f = *(const short8*)&Kb[(c * 16 + ln) * 64 + ((quad ^ (ln & 7)) * 8)];
            short8 k1f = *(const short8*)&Kb[(c * 16 + ln) * 64 + (((4 + quad) ^ (ln & 7)) * 8)];
            f32x4 s = {0, 0, 0, 0};
            s = __builtin_amdgcn_mfma_f32_16x16x32_bf16(aQ0, k0f, s, 0, 0, 0);
            s = __builtin_amdgcn_mfma_f32_16x16x32_bf16(aQ1, k1f, s, 0, 0, 0);
            bool diag = partial && (kbase + 15 > q0);
#pragma unroll
            for (int r = 0; r < 4; ++r) {
                float e = __builtin_exp2f(s[r] * c_exp);
                if (diag && (kbase + ln > q0 + quad * 4 + r)) e = 0.f;  // causal
                lsum[r] += e;
                int row = quad * 4 + r;
                pb[row * 64 + (((c * 2 + (ln >> 3)) ^ (row & 7)) * 8) + (ln & 7)] =
                    (unsigned short)(__float_as_uint(e) >> 16);        // bf16 trunc
            }
        }
        short8 aP0 = *(const short8*)&pb[ln * 64 + ((quad ^ (ln & 7)) * 8)];
        short8 aP1 = *(const short8*)&pb[ln * 64 + (((4 + quad) ^ (ln & 7)) * 8)];
#pragma unroll
        for (int nt = 0; nt < 4; ++nt) {
            short8 v0 = *(const short8*)&Vf[(nt * 16 + ln) * 64 + ((quad ^ (ln & 7)) * 8)];
            short8 v1 = *(const short8*)&Vf[(nt * 16 + ln) * 64 + (((4 + quad) ^ (ln & 7)) * 8)];
            o[nt] = __builtin_amdgcn_mfma_f32_16x16x32_bf16(aP0, v0, o[nt], 0, 0, 0);
            o[nt] = __builtin_amdgcn_mfma_f32_16x16x32_bf16(aP1, v1, o[nt], 0, 0, 0);
        }
    };

    stageKV(0, 0);
    for (int it = 0; it < jg; ++it) {          // full steps, mask-free
        __syncthreads();
        stageKV((it + 1) * 64, (it + 1) & 1);
        computeStep(it * 64, it & 1, false);
    }
    __syncthreads();
    computeStep(jg * 64, jg & 1, true);        // the one partial step

    // epilogue: reduce l across the 16 lanes of each quad, then Y = O / l
    for (int off = 1; off < 16; off <<= 1)
#pragma unroll
        for (int r = 0; r < 4; ++r) lsum[r] += __shfl_xor(lsum[r], off);
#pragma unroll
    for (int r = 0; r < 4; ++r) {
        float inv = 1.0f / lsum[r];
        int t_idx = q0 + quad * 4 + r;
        unsigned short* yp = Y + (baseRow + t_idx) * DM + h * HD + ln;
        for (int nt = 0; nt < 4; ++nt)
            yp[nt * 16] = f2bf(o[nt][r] * inv);
    }
}

extern "C" void kernel_launch(void* const* d_in, const int* in_sizes, int n_in,
                              void* d_out, int out_size, void* d_ws, size_t ws_size,
                              hipStream_t stream) {
    const float* x  = (const float*)d_in[0];
    const float* Wq = (const float*)d_in[1];
    const float* Wk = (const float*)d_in[2];
    const float* Wv = (const float*)d_in[3];
    const float* Wo = (const float*)d_in[4];
    float* out = (float*)d_out;

    char* ws = (char*)d_ws;
    // workspace (22.8 MB): slot0 is xb until qkv-gemm completes, then y.
    unsigned short* xb  = (unsigned short*)(ws);                // 4096x1024 bf16 (8 MB)
    unsigned short* y   = (unsigned short*)(ws);                // alias: attn out
    unsigned short* wtq = (unsigned short*)(ws + 8388608);      // 1152x1024 bf16
    unsigned short* wot = (unsigned short*)(ws + 10747904);     // 1024x1024 bf16
    unsigned short* qkv = (unsigned short*)(ws + 12845056);     // 4096x1152 bf16
    unsigned short* Vt  = (unsigned short*)(ws + 22282240);     // 2x64x2048 bf16 (0.5 MB)

    const int BT = BATCH * SEQ;  // 4096 rows

    hipLaunchKernelGGL(cast_x_kernel, dim3(BT * DM / 4 / 256), dim3(256), 0, stream,
                       x, xb, BT * DM);
    hipLaunchKernelGGL(prep_w_kernel, dim3(DM / 32, DM / 32, 4), dim3(256), 0, stream,
                       Wq, Wk, Wv, Wo, wtq, wot);

    // QKV = x @ [Wq|Wk|Wv] -> bf16; V cols also written transposed to Vt
    // 576 blocks = 8 XCDs x 4 row-strips x 18 cols (XCD-aware remap inside)
    hipLaunchKernelGGL(gemm_direct_kernel, dim3((BT / 128) * (LDQ / 64)), dim3(256), 0, stream,
                       xb, wtq, (void*)qkv, Vt, LDQ, 1, LDQ / 64);

    // flash attention (R0 4-wave, 64-key dbuf steps) -> y bf16 (overwrites xb)
    hipLaunchKernelGGL(attn_kernel, dim3(32 * 32), dim3(256), 0, stream,
                       qkv, Vt, y);

    // out = y @ Wo -> fp32; 512 blocks = 8 XCDs x 4 row-strips x 16 cols
    hipLaunchKernelGGL(gemm_direct_kernel, dim3((BT / 128) * (DM / 64)), dim3(256), 0, stream,
                       y, wot, (void*)out, nullptr, DM, 0, DM / 64);
}

// Round 7
// 196.380 us; speedup vs baseline: 1.2381x; 1.2381x over previous
//
#include <hip/hip_runtime.h>
#include <hip/hip_bf16.h>
#include <stdint.h>

typedef short short8 __attribute__((ext_vector_type(8)));
typedef float f32x4 __attribute__((ext_vector_type(4)));

// Problem constants
constexpr int SEQ   = 2048;   // T
constexpr int DM    = 1024;   // model dim
constexpr int NHEAD = 16;
constexpr int HD    = 64;     // head dim
constexpr int LDQ   = 1152;   // QKV row stride: 1024 Q | 64 K | 64 V
constexpr int BATCH = 2;
constexpr int BT    = BATCH * SEQ;   // 4096 GEMM rows

__device__ __forceinline__ unsigned short f2bf(float f) {
    union { float f; uint32_t u; } v; v.f = f;
    uint32_t u = v.u;
    uint32_t r = (u + 0x7fffu + ((u >> 16) & 1u)) >> 16;
    return (unsigned short)r;
}

// async global->LDS, 16B per lane (attn staging only).
typedef __attribute__((address_space(1))) const void gvoid_t;
typedef __attribute__((address_space(3))) void lvoid_t;
__device__ __forceinline__ void gload16(const void* g, void* l) {
    __builtin_amdgcn_global_load_lds((gvoid_t*)g, (lvoid_t*)l, 16, 0, 0);
}

// -------- cast + PACK x: fp32 [BT][DM] -> bf16 packed [DM/32][BT][32] -------
// Packed (fragment-native) layout: element (m, k) lives at
//   xp[((k>>5)*BT + m)*32 + (k&31)].
// One 16x16x32 MFMA's A-operand (16 rows x 32 k) is then 1 KB CONTIGUOUS:
// lane(ln,quad) reads 16B at +ln*64 + quad*16 -- fully coalesced (fixes R6's
// 16-way gather, which left gemm_direct at VALUBusy 2.3% / MfmaUtil 4.9%).
// Reads: thread m pulls 128B contiguous from its row (8x float4).
// Writes: consecutive threads (m) -> consecutive 64B chunks: 4KB/wave.
__global__ __launch_bounds__(256) void cast_pack_x_kernel(
        const float* __restrict__ x, unsigned short* __restrict__ xp) {
    int k32 = blockIdx.y;                       // 0..31
    int m   = blockIdx.x * 256 + threadIdx.x;   // 0..4095
    const float* src = x + (size_t)m * DM + k32 * 32;
    unsigned short* dst = xp + ((size_t)k32 * BT + m) * 32;
#pragma unroll
    for (int gq = 0; gq < 4; ++gq) {
        float4 f0 = *(const float4*)(src + gq * 8);
        float4 f1 = *(const float4*)(src + gq * 8 + 4);
        short8 w;
        w[0] = f2bf(f0.x); w[1] = f2bf(f0.y); w[2] = f2bf(f0.z); w[3] = f2bf(f0.w);
        w[4] = f2bf(f1.x); w[5] = f2bf(f1.y); w[6] = f2bf(f1.z); w[7] = f2bf(f1.w);
        *(short8*)(dst + gq * 8) = w;
    }
}

// ---- weight prep: cast + PACK Wq,Wk,Wv,Wo -> [K/32][N][32] bf16 ----
// W is stored [K][C] (k-major) so no transpose staging needed: thread c
// gathers 32 k-rows at its column (each read coalesced across the wave),
// packs 64B, writes one contiguous 64B chunk (consecutive c -> consecutive
// chunks: perfect 4KB/wave store). wtq packs [Wq|Wk|Wv] to N=1152.
__global__ __launch_bounds__(256) void prep_w_kernel(
        const float* __restrict__ Wq, const float* __restrict__ Wk,
        const float* __restrict__ Wv, const float* __restrict__ Wo,
        unsigned short* __restrict__ wtq, unsigned short* __restrict__ wot) {
    int z = blockIdx.z;
    const float* W; unsigned short* outp; int C, Ntot, noff;
    if (z == 0)      { W = Wq; outp = wtq; C = DM; Ntot = LDQ; noff = 0; }
    else if (z == 1) { W = Wk; outp = wtq; C = HD; Ntot = LDQ; noff = DM; }
    else if (z == 2) { W = Wv; outp = wtq; C = HD; Ntot = LDQ; noff = DM + HD; }
    else             { W = Wo; outp = wot; C = DM; Ntot = DM;  noff = 0; }
    int k32 = blockIdx.y;                       // 0..31
    int c = blockIdx.x * 256 + threadIdx.x;
    if (c >= C) return;
    const float* src = W + (size_t)k32 * 32 * C + c;
    unsigned short* dst = outp + ((size_t)k32 * Ntot + noff + c) * 32;
#pragma unroll
    for (int gq = 0; gq < 4; ++gq) {
        short8 w;
#pragma unroll
        for (int e = 0; e < 8; ++e)
            w[e] = f2bf(src[(size_t)(gq * 8 + e) * C]);
        *(short8*)(dst + gq * 8) = w;
    }
}

// ---- GEMM, packed-direct (NO LDS, NO barriers): C = A @ B, K=1024 ----
// A packed [32][M][32], B packed [32][N][32] (fragment-native, see above).
// Each wave owns a 64x32 output tile (acc[4][2]); per 32-k chunk it issues
// 4 A + 2 B coalesced dwordx4 loads (each a 1KB wave segment, L2-served)
// feeding 8 MFMAs, explicit 2-stage register rotation (static indices).
// No __shared__, no __syncthreads, no vmcnt(0) drains: the compiler emits
// counted waitcnts for plain loads, so each wave free-runs its own pipeline
// -- removing the per-K-step barrier-drain that pinned every LDS-staged
// variant (R0-R4) at ~50us/GEMM, and the gather stall that broke R6.
// Block = 2x2 waves = 128x64 tile; bijective XCD remap keeps each XCD's
// A row-strip (1MB) L2-resident across its 16-18 column blocks.
__global__ __launch_bounds__(256) void gemm_packed_kernel(
        const unsigned short* __restrict__ Ap,
        const unsigned short* __restrict__ Bp,
        void* __restrict__ Cout,
        unsigned short* __restrict__ VtOut,
        int M, int N, int out_bf16, int ncols) {
    int lane = threadIdx.x & 63, wave = threadIdx.x >> 6;
    int ln = lane & 15, quad = lane >> 4;
    int wm = wave >> 1, wn = wave & 1;

    // XCD-aware block remap (bijective: gridDim.x % 8 == 0)
    int g = blockIdx.x;
    int xcd = g & 7, idx = g >> 3;
    int rows_per_xcd = (int)(gridDim.x >> 3) / ncols;
    int row = xcd * rows_per_xcd + idx / ncols;
    int col = idx % ncols;
    int m0 = row * 128, n0 = col * 64;

    const size_t sA = (size_t)M * 32;     // shorts per k32 step
    const size_t sB = (size_t)N * 32;
    const unsigned short* aB = Ap + (size_t)(m0 + wm * 64 + ln) * 32 + quad * 8;
    const unsigned short* bB = Bp + (size_t)(n0 + wn * 32 + ln) * 32 + quad * 8;

    f32x4 acc[4][2];
#pragma unroll
    for (int i = 0; i < 4; ++i)
#pragma unroll
        for (int j = 0; j < 2; ++j) acc[i][j] = f32x4{0, 0, 0, 0};

    short8 a0[4], b0[2], a1[4], b1[2];
#define LDA(dst, kc) { \
    const unsigned short* p_ = aB + (size_t)(kc) * sA; \
    dst[0] = *(const short8*)(p_);        dst[1] = *(const short8*)(p_ + 512); \
    dst[2] = *(const short8*)(p_ + 1024); dst[3] = *(const short8*)(p_ + 1536); }
#define LDB(dst, kc) { \
    const unsigned short* p_ = bB + (size_t)(kc) * sB; \
    dst[0] = *(const short8*)(p_);        dst[1] = *(const short8*)(p_ + 512); }

    LDA(a0, 0); LDB(b0, 0);
#pragma unroll
    for (int kc = 0; kc < 32; kc += 2) {
        LDA(a1, kc + 1); LDB(b1, kc + 1);
#pragma unroll
        for (int mt = 0; mt < 4; ++mt)
#pragma unroll
            for (int nt = 0; nt < 2; ++nt)
                acc[mt][nt] = __builtin_amdgcn_mfma_f32_16x16x32_bf16(
                    a0[mt], b0[nt], acc[mt][nt], 0, 0, 0);
        if (kc + 2 < 32) { LDA(a0, kc + 2); LDB(b0, kc + 2); }
#pragma unroll
        for (int mt = 0; mt < 4; ++mt)
#pragma unroll
            for (int nt = 0; nt < 2; ++nt)
                acc[mt][nt] = __builtin_amdgcn_mfma_f32_16x16x32_bf16(
                    a1[mt], b1[nt], acc[mt][nt], 0, 0, 0);
    }
#undef LDA
#undef LDB

    if (out_bf16) {
        unsigned short* C = (unsigned short*)Cout;
#pragma unroll
        for (int mt = 0; mt < 4; ++mt)
#pragma unroll
            for (int nt = 0; nt < 2; ++nt)
#pragma unroll
                for (int r = 0; r < 4; ++r) {
                    int rr = m0 + wm * 64 + mt * 16 + quad * 4 + r;
                    int cc = n0 + wn * 32 + nt * 16 + ln;
                    unsigned short hv = f2bf(acc[mt][nt][r]);
                    C[(size_t)rr * N + cc] = hv;
                    if (VtOut != nullptr && cc >= DM + HD) {  // V cols: also transposed
                        int d = cc - (DM + HD);               // 0..63
                        int bb = rr >> 11, s = rr & 2047;
                        VtOut[((size_t)bb * HD + d) * SEQ + s] = hv;
                    }
                }
    } else {
        float* C = (float*)Cout;
#pragma unroll
        for (int mt = 0; mt < 4; ++mt)
#pragma unroll
            for (int nt = 0; nt < 2; ++nt)
#pragma unroll
                for (int r = 0; r < 4; ++r) {
                    int rr = m0 + wm * 64 + mt * 16 + quad * 4 + r;
                    int cc = n0 + wn * 32 + nt * 16 + ln;
                    C[(size_t)rr * N + cc] = acc[mt][nt][r];
                }
    }
}

// ---------------- flash attention (multi-query, causal) ----------------
// R0 design verbatim (best measured: 51.4 us; every structural variant
// regressed: 8-wave 54.4, 2-barrier pipeline 60.5, 32-row 68.3) EXCEPT the
// epilogue, which now writes y in the packed [DM/32][BT][32] layout so the
// out-projection GEMM reads its A-fragments coalesced. Same bytes, new
// addresses: col=h*64+nt*16+ln -> y[((h*2+(nt>>1))*BT+row)*32+(nt&1)*16+ln].
__global__ __launch_bounds__(256) void attn_kernel(
        const unsigned short* __restrict__ QKV,
        const unsigned short* __restrict__ Vt,
        unsigned short* __restrict__ Y) {
    __shared__ unsigned short ldsK[2][64 * 64];
    __shared__ unsigned short ldsV[2][64 * 64];
    __shared__ unsigned short pbuf[4][16 * 64];   // swizzled, per-wave

    int lane = threadIdx.x & 63, wave = threadIdx.x >> 6;
    int ln = lane & 15, quad = lane >> 4;
    int bid = blockIdx.x;
    int jg = 31 - (bid >> 5);             // heavy-first
    int bh = bid & 31;
    int h = bh & 15, b = bh >> 4;
    int q0 = (jg * 4 + wave) * 16;
    const size_t baseRow = (size_t)b * SEQ;
    const unsigned short* Vb = Vt + (size_t)b * HD * SEQ;

    int t = threadIdx.x;
    int trow = t >> 3, tcb = t & 7;
    int cbg = tcb ^ (trow & 7);
    const unsigned short* gK = QKV + (baseRow + trow) * LDQ + DM + cbg * 8;
    const unsigned short* gV = Vb + (size_t)trow * SEQ + cbg * 8;
    int dstoff = trow * 64 + tcb * 8;

    auto stageKV = [&](int s0n, int buf) {
#pragma unroll
        for (int rr = 0; rr < 2; ++rr) {
            gload16(gK + (size_t)(s0n + 32 * rr) * LDQ, &ldsK[buf][dstoff + rr * 2048]);
            gload16(gV + (size_t)32 * rr * SEQ + s0n,   &ldsV[buf][dstoff + rr * 2048]);
        }
    };

    // Q fragments (A-layout)
    short8 aQ0, aQ1;
    {
        const unsigned short* qp = QKV + (baseRow + q0 + ln) * LDQ + h * HD + quad * 8;
        aQ0 = *(const short8*)(qp);
        aQ1 = *(const short8*)(qp + 32);
    }

    float lsum[4] = {0.f, 0.f, 0.f, 0.f};
    f32x4 o[4];
    for (int nt = 0; nt < 4; ++nt) o[nt] = f32x4{0, 0, 0, 0};

    const float c_exp = 0.1803368802f;    // 0.125 * log2(e)
    unsigned short* pb = &pbuf[wave][0];

    auto computeStep = [&](int s0, int buf, bool partial) {
        const unsigned short* Kb = ldsK[buf];
        const unsigned short* Vf = ldsV[buf];
#pragma unroll
        for (int c = 0; c < 4; ++c) {
            int kbase = s0 + c * 16;
            if (partial && kbase > q0 + 15) {   // fully masked tile: zero P
#pragma unroll
                for (int r = 0; r < 4; ++r) {
                    int row = quad * 4 + r;
                    pb[row * 64 + (((c * 2 + (ln >> 3)) ^ (row & 7)) * 8) + (ln & 7)] = 0;
                }
                continue;
            }
            short8 k0f = *(const short8*)&Kb[(c * 16 + ln) * 64 + ((quad ^ (ln & 7)) * 8)];
            short8 k1f = *(const short8*)&Kb[(c * 16 + ln) * 64 + (((4 + quad) ^ (ln & 7)) * 8)];
            f32x4 s = {0, 0, 0, 0};
            s = __builtin_amdgcn_mfma_f32_16x16x32_bf16(aQ0, k0f, s, 0, 0, 0);
            s = __builtin_amdgcn_mfma_f32_16x16x32_bf16(aQ1, k1f, s, 0, 0, 0);
            bool diag = partial && (kbase + 15 > q0);
#pragma unroll
            for (int r = 0; r < 4; ++r) {
                float e = __builtin_exp2f(s[r] * c_exp);
                if (diag && (kbase + ln > q0 + quad * 4 + r)) e = 0.f;  // causal
                lsum[r] += e;
                int row = quad * 4 + r;
                pb[row * 64 + (((c * 2 + (ln >> 3)) ^ (row & 7)) * 8) + (ln & 7)] =
                    (unsigned short)(__float_as_uint(e) >> 16);        // bf16 trunc
            }
        }
        short8 aP0 = *(const short8*)&pb[ln * 64 + ((quad ^ (ln & 7)) * 8)];
        short8 aP1 = *(const short8*)&pb[ln * 64 + (((4 + quad) ^ (ln & 7)) * 8)];
#pragma unroll
        for (int nt = 0; nt < 4; ++nt) {
            short8 v0 = *(const short8*)&Vf[(nt * 16 + ln) * 64 + ((quad ^ (ln & 7)) * 8)];
            short8 v1 = *(const short8*)&Vf[(nt * 16 + ln) * 64 + (((4 + quad) ^ (ln & 7)) * 8)];
            o[nt] = __builtin_amdgcn_mfma_f32_16x16x32_bf16(aP0, v0, o[nt], 0, 0, 0);
            o[nt] = __builtin_amdgcn_mfma_f32_16x16x32_bf16(aP1, v1, o[nt], 0, 0, 0);
        }
    };

    stageKV(0, 0);
    for (int it = 0; it < jg; ++it) {          // full steps, mask-free
        __syncthreads();
        stageKV((it + 1) * 64, (it + 1) & 1);
        computeStep(it * 64, it & 1, false);
    }
    __syncthreads();
    computeStep(jg * 64, jg & 1, true);        // the one partial step

    // epilogue: reduce l, then write Y = O / l in PACKED layout
    for (int off = 1; off < 16; off <<= 1)
#pragma unroll
        for (int r = 0; r < 4; ++r) lsum[r] += __shfl_xor(lsum[r], off);
#pragma unroll
    for (int r = 0; r < 4; ++r) {
        float inv = 1.0f / lsum[r];
        size_t row = baseRow + q0 + quad * 4 + r;
#pragma unroll
        for (int nt = 0; nt < 4; ++nt) {
            int chunk = h * 2 + (nt >> 1);
            Y[((size_t)chunk * BT + row) * 32 + (nt & 1) * 16 + ln] =
                f2bf(o[nt][r] * inv);
        }
    }
}

extern "C" void kernel_launch(void* const* d_in, const int* in_sizes, int n_in,
                              void* d_out, int out_size, void* d_ws, size_t ws_size,
                              hipStream_t stream) {
    const float* x  = (const float*)d_in[0];
    const float* Wq = (const float*)d_in[1];
    const float* Wk = (const float*)d_in[2];
    const float* Wv = (const float*)d_in[3];
    const float* Wo = (const float*)d_in[4];
    float* out = (float*)d_out;

    char* ws = (char*)d_ws;
    // workspace (22.8 MB): slot0 is packed-x until qkv-gemm completes, then packed-y.
    unsigned short* xb  = (unsigned short*)(ws);                // packed x (8 MB)
    unsigned short* y   = (unsigned short*)(ws);                // alias: packed attn out
    unsigned short* wtq = (unsigned short*)(ws + 8388608);      // packed [Wq|Wk|Wv]
    unsigned short* wot = (unsigned short*)(ws + 10747904);     // packed Wo
    unsigned short* qkv = (unsigned short*)(ws + 12845056);     // 4096x1152 bf16 row-major
    unsigned short* Vt  = (unsigned short*)(ws + 22282240);     // 2x64x2048 bf16 (0.5 MB)

    hipLaunchKernelGGL(cast_pack_x_kernel, dim3(BT / 256, 32), dim3(256), 0, stream,
                       x, xb);
    hipLaunchKernelGGL(prep_w_kernel, dim3(DM / 256, 32, 4), dim3(256), 0, stream,
                       Wq, Wk, Wv, Wo, wtq, wot);

    // QKV = x @ [Wq|Wk|Wv] -> bf16 row-major; V cols also written transposed to Vt
    // 576 blocks = 8 XCDs x 4 row-strips x 18 cols (XCD-aware remap inside)
    hipLaunchKernelGGL(gemm_packed_kernel, dim3((BT / 128) * (LDQ / 64)), dim3(256), 0, stream,
                       xb, wtq, (void*)qkv, Vt, BT, LDQ, 1, LDQ / 64);

    // flash attention (R0 4-wave) -> packed y (overwrites packed x, now dead)
    hipLaunchKernelGGL(attn_kernel, dim3(32 * 32), dim3(256), 0, stream,
                       qkv, Vt, y);

    // out = y @ Wo -> fp32; 512 blocks = 8 XCDs x 4 row-strips x 16 cols
    hipLaunchKernelGGL(gemm_packed_kernel, dim3((BT / 128) * (DM / 64)), dim3(256), 0, stream,
                       y, wot, (void*)out, nullptr, BT, DM, 0, DM / 64);
}

// Round 8
// 195.276 us; speedup vs baseline: 1.2451x; 1.0057x over previous
//
#include <hip/hip_runtime.h>
#include <hip/hip_bf16.h>
#include <stdint.h>

typedef short short8 __attribute__((ext_vector_type(8)));
typedef float f32x4 __attribute__((ext_vector_type(4)));

// Problem constants
constexpr int SEQ   = 2048;   // T
constexpr int DM    = 1024;   // model dim
constexpr int NHEAD = 16;
constexpr int HD    = 64;     // head dim
constexpr int LDQ   = 1152;   // QKV row stride: 1024 Q | 64 K | 64 V
constexpr int BATCH = 2;
constexpr int BT    = BATCH * SEQ;   // 4096 GEMM rows

__device__ __forceinline__ unsigned short f2bf(float f) {
    union { float f; uint32_t u; } v; v.f = f;
    uint32_t u = v.u;
    uint32_t r = (u + 0x7fffu + ((u >> 16) & 1u)) >> 16;
    return (unsigned short)r;
}

// async global->LDS, 16B per lane (attn staging only).
typedef __attribute__((address_space(1))) const void gvoid_t;
typedef __attribute__((address_space(3))) void lvoid_t;
__device__ __forceinline__ void gload16(const void* g, void* l) {
    __builtin_amdgcn_global_load_lds((gvoid_t*)g, (lvoid_t*)l, 16, 0, 0);
}

// -------- cast + PACK x: fp32 [BT][DM] -> bf16 packed [DM/32][BT][32] -------
// Packed (fragment-native): element (m,k) -> xp[((k>>5)*BT + m)*32 + (k&31)].
// One 16x16x32 MFMA A-operand (16 rows x 32 k) = 1 KB contiguous; lane
// (ln,quad) reads 16B at +ln*64+quad*16 -- fully coalesced.
__global__ __launch_bounds__(256) void cast_pack_x_kernel(
        const float* __restrict__ x, unsigned short* __restrict__ xp) {
    int k32 = blockIdx.y;                       // 0..31
    int m   = blockIdx.x * 256 + threadIdx.x;   // 0..4095
    const float* src = x + (size_t)m * DM + k32 * 32;
    unsigned short* dst = xp + ((size_t)k32 * BT + m) * 32;
#pragma unroll
    for (int gq = 0; gq < 4; ++gq) {
        float4 f0 = *(const float4*)(src + gq * 8);
        float4 f1 = *(const float4*)(src + gq * 8 + 4);
        short8 w;
        w[0] = f2bf(f0.x); w[1] = f2bf(f0.y); w[2] = f2bf(f0.z); w[3] = f2bf(f0.w);
        w[4] = f2bf(f1.x); w[5] = f2bf(f1.y); w[6] = f2bf(f1.z); w[7] = f2bf(f1.w);
        *(short8*)(dst + gq * 8) = w;
    }
}

// ---- weight prep: cast + PACK Wq,Wk,Wv,Wo -> [K/32][N][32] bf16 ----
__global__ __launch_bounds__(256) void prep_w_kernel(
        const float* __restrict__ Wq, const float* __restrict__ Wk,
        const float* __restrict__ Wv, const float* __restrict__ Wo,
        unsigned short* __restrict__ wtq, unsigned short* __restrict__ wot) {
    int z = blockIdx.z;
    const float* W; unsigned short* outp; int C, Ntot, noff;
    if (z == 0)      { W = Wq; outp = wtq; C = DM; Ntot = LDQ; noff = 0; }
    else if (z == 1) { W = Wk; outp = wtq; C = HD; Ntot = LDQ; noff = DM; }
    else if (z == 2) { W = Wv; outp = wtq; C = HD; Ntot = LDQ; noff = DM + HD; }
    else             { W = Wo; outp = wot; C = DM; Ntot = DM;  noff = 0; }
    int k32 = blockIdx.y;                       // 0..31
    int c = blockIdx.x * 256 + threadIdx.x;
    if (c >= C) return;
    const float* src = W + (size_t)k32 * 32 * C + c;
    unsigned short* dst = outp + ((size_t)k32 * Ntot + noff + c) * 32;
#pragma unroll
    for (int gq = 0; gq < 4; ++gq) {
        short8 w;
#pragma unroll
        for (int e = 0; e < 8; ++e)
            w[e] = f2bf(src[(size_t)(gq * 8 + e) * C]);
        *(short8*)(dst + gq * 8) = w;
    }
}

// ---- GEMM, packed-direct (NO LDS, NO barriers), 4-STAGE pipeline ----
// R8: R7's 2-stage register rotation left each wave stalling ~150cy/chunk
// (cover = 1 MFMA block ~40cy vs L2 latency ~200cy; VGPR_Count was only 48).
// Now 4 named stages: loads for chunk c+3 issue while chunk c computes --
// ~18 loads in flight, cover ~3 MFMA blocks/wave x 2.25 waves/SIMD > 200cy.
// A packed [32][BT][32], B packed [32][NN][32]; per chunk 4 A + 2 B coalesced
// dwordx4 (1KB wave segments, L2-served) + 8 MFMA. Static stage names only
// (rule #20); NN compile-time so stage strides fold. Compiler emits counted
// s_waitcnt per stage (no drain-0, no barriers).
// Block = 2x2 waves = 128x64 tile; bijective XCD remap (grid%8==0).
template<int NN>
__global__ __launch_bounds__(256) void gemm_packed_kernel(
        const unsigned short* __restrict__ Ap,
        const unsigned short* __restrict__ Bp,
        void* __restrict__ Cout,
        unsigned short* __restrict__ VtOut,
        int out_bf16, int ncols) {
    int lane = threadIdx.x & 63, wave = threadIdx.x >> 6;
    int ln = lane & 15, quad = lane >> 4;
    int wm = wave >> 1, wn = wave & 1;

    // XCD-aware block remap (bijective: gridDim.x % 8 == 0)
    int g = blockIdx.x;
    int xcd = g & 7, idx = g >> 3;
    int rows_per_xcd = (int)(gridDim.x >> 3) / ncols;
    int row = xcd * rows_per_xcd + idx / ncols;
    int col = idx % ncols;
    int m0 = row * 128, n0 = col * 64;

    constexpr size_t sA = (size_t)BT * 32;    // shorts per k32 step
    constexpr size_t sB = (size_t)NN * 32;
    const unsigned short* aB = Ap + (size_t)(m0 + wm * 64 + ln) * 32 + quad * 8;
    const unsigned short* bB = Bp + (size_t)(n0 + wn * 32 + ln) * 32 + quad * 8;

    f32x4 acc[4][2];
#pragma unroll
    for (int i = 0; i < 4; ++i)
#pragma unroll
        for (int j = 0; j < 2; ++j) acc[i][j] = f32x4{0, 0, 0, 0};

    short8 a0[4], a1[4], a2[4], a3[4];
    short8 b0[2], b1[2], b2[2], b3[2];

    auto LD = [&](short8 (&as)[4], short8 (&bs)[2], int kc) {
        const unsigned short* pa = aB + (size_t)kc * sA;
        as[0] = *(const short8*)(pa);        as[1] = *(const short8*)(pa + 512);
        as[2] = *(const short8*)(pa + 1024); as[3] = *(const short8*)(pa + 1536);
        const unsigned short* pb = bB + (size_t)kc * sB;
        bs[0] = *(const short8*)(pb);        bs[1] = *(const short8*)(pb + 512);
    };
    auto MM = [&](short8 (&as)[4], short8 (&bs)[2]) {
#pragma unroll
        for (int mt = 0; mt < 4; ++mt)
#pragma unroll
            for (int nt = 0; nt < 2; ++nt)
                acc[mt][nt] = __builtin_amdgcn_mfma_f32_16x16x32_bf16(
                    as[mt], bs[nt], acc[mt][nt], 0, 0, 0);
    };

    LD(a0, b0, 0); LD(a1, b1, 1); LD(a2, b2, 2);
#pragma unroll
    for (int kc = 0; kc < 32; kc += 4) {
        if (kc + 3 < 32) LD(a3, b3, kc + 3);
        MM(a0, b0);
        if (kc + 4 < 32) LD(a0, b0, kc + 4);
        MM(a1, b1);
        if (kc + 5 < 32) LD(a1, b1, kc + 5);
        MM(a2, b2);
        if (kc + 6 < 32) LD(a2, b2, kc + 6);
        MM(a3, b3);
    }

    if (out_bf16) {
        unsigned short* C = (unsigned short*)Cout;
#pragma unroll
        for (int mt = 0; mt < 4; ++mt)
#pragma unroll
            for (int nt = 0; nt < 2; ++nt)
#pragma unroll
                for (int r = 0; r < 4; ++r) {
                    int rr = m0 + wm * 64 + mt * 16 + quad * 4 + r;
                    int cc = n0 + wn * 32 + nt * 16 + ln;
                    unsigned short hv = f2bf(acc[mt][nt][r]);
                    C[(size_t)rr * NN + cc] = hv;
                    if (VtOut != nullptr && cc >= DM + HD) {  // V cols: also transposed
                        int d = cc - (DM + HD);               // 0..63
                        int bb = rr >> 11, s = rr & 2047;
                        VtOut[((size_t)bb * HD + d) * SEQ + s] = hv;
                    }
                }
    } else {
        float* C = (float*)Cout;
#pragma unroll
        for (int mt = 0; mt < 4; ++mt)
#pragma unroll
            for (int nt = 0; nt < 2; ++nt)
#pragma unroll
                for (int r = 0; r < 4; ++r) {
                    int rr = m0 + wm * 64 + mt * 16 + quad * 4 + r;
                    int cc = n0 + wn * 32 + nt * 16 + ln;
                    C[(size_t)rr * NN + cc] = acc[mt][nt][r];
                }
    }
}

// ---------------- flash attention (multi-query, causal) ----------------
// R0 design verbatim (best measured: 51.4 us) except the epilogue writes y
// in the packed [DM/32][BT][32] layout for the out-projection's coalesced
// A-fragment reads. Same bytes, new addresses.
__global__ __launch_bounds__(256) void attn_kernel(
        const unsigned short* __restrict__ QKV,
        const unsigned short* __restrict__ Vt,
        unsigned short* __restrict__ Y) {
    __shared__ unsigned short ldsK[2][64 * 64];
    __shared__ unsigned short ldsV[2][64 * 64];
    __shared__ unsigned short pbuf[4][16 * 64];   // swizzled, per-wave

    int lane = threadIdx.x & 63, wave = threadIdx.x >> 6;
    int ln = lane & 15, quad = lane >> 4;
    int bid = blockIdx.x;
    int jg = 31 - (bid >> 5);             // heavy-first
    int bh = bid & 31;
    int h = bh & 15, b = bh >> 4;
    int q0 = (jg * 4 + wave) * 16;
    const size_t baseRow = (size_t)b * SEQ;
    const unsigned short* Vb = Vt + (size_t)b * HD * SEQ;

    int t = threadIdx.x;
    int trow = t >> 3, tcb = t & 7;
    int cbg = tcb ^ (trow & 7);
    const unsigned short* gK = QKV + (baseRow + trow) * LDQ + DM + cbg * 8;
    const unsigned short* gV = Vb + (size_t)trow * SEQ + cbg * 8;
    int dstoff = trow * 64 + tcb * 8;

    auto stageKV = [&](int s0n, int buf) {
#pragma unroll
        for (int rr = 0; rr < 2; ++rr) {
            gload16(gK + (size_t)(s0n + 32 * rr) * LDQ, &ldsK[buf][dstoff + rr * 2048]);
            gload16(gV + (size_t)32 * rr * SEQ + s0n,   &ldsV[buf][dstoff + rr * 2048]);
        }
    };

    // Q fragments (A-layout)
    short8 aQ0, aQ1;
    {
        const unsigned short* qp = QKV + (baseRow + q0 + ln) * LDQ + h * HD + quad * 8;
        aQ0 = *(const short8*)(qp);
        aQ1 = *(const short8*)(qp + 32);
    }

    float lsum[4] = {0.f, 0.f, 0.f, 0.f};
    f32x4 o[4];
    for (int nt = 0; nt < 4; ++nt) o[nt] = f32x4{0, 0, 0, 0};

    const float c_exp = 0.1803368802f;    // 0.125 * log2(e)
    unsigned short* pb = &pbuf[wave][0];

    auto computeStep = [&](int s0, int buf, bool partial) {
        const unsigned short* Kb = ldsK[buf];
        const unsigned short* Vf = ldsV[buf];
#pragma unroll
        for (int c = 0; c < 4; ++c) {
            int kbase = s0 + c * 16;
            if (partial && kbase > q0 + 15) {   // fully masked tile: zero P
#pragma unroll
                for (int r = 0; r < 4; ++r) {
                    int row = quad * 4 + r;
                    pb[row * 64 + (((c * 2 + (ln >> 3)) ^ (row & 7)) * 8) + (ln & 7)] = 0;
                }
                continue;
            }
            short8 k0f = *(const short8*)&Kb[(c * 16 + ln) * 64 + ((quad ^ (ln & 7)) * 8)];
            short8 k1f = *(const short8*)&Kb[(c * 16 + ln) * 64 + (((4 + quad) ^ (ln & 7)) * 8)];
            f32x4 s = {0, 0, 0, 0};
            s = __builtin_amdgcn_mfma_f32_16x16x32_bf16(aQ0, k0f, s, 0, 0, 0);
            s = __builtin_amdgcn_mfma_f32_16x16x32_bf16(aQ1, k1f, s, 0, 0, 0);
            bool diag = partial && (kbase + 15 > q0);
#pragma unroll
            for (int r = 0; r < 4; ++r) {
                float e = __builtin_exp2f(s[r] * c_exp);
                if (diag && (kbase + ln > q0 + quad * 4 + r)) e = 0.f;  // causal
                lsum[r] += e;
                int row = quad * 4 + r;
                pb[row * 64 + (((c * 2 + (ln >> 3)) ^ (row & 7)) * 8) + (ln & 7)] =
                    (unsigned short)(__float_as_uint(e) >> 16);        // bf16 trunc
            }
        }
        short8 aP0 = *(const short8*)&pb[ln * 64 + ((quad ^ (ln & 7)) * 8)];
        short8 aP1 = *(const short8*)&pb[ln * 64 + (((4 + quad) ^ (ln & 7)) * 8)];
#pragma unroll
        for (int nt = 0; nt < 4; ++nt) {
            short8 v0 = *(const short8*)&Vf[(nt * 16 + ln) * 64 + ((quad ^ (ln & 7)) * 8)];
            short8 v1 = *(const short8*)&Vf[(nt * 16 + ln) * 64 + (((4 + quad) ^ (ln & 7)) * 8)];
            o[nt] = __builtin_amdgcn_mfma_f32_16x16x32_bf16(aP0, v0, o[nt], 0, 0, 0);
            o[nt] = __builtin_amdgcn_mfma_f32_16x16x32_bf16(aP1, v1, o[nt], 0, 0, 0);
        }
    };

    stageKV(0, 0);
    for (int it = 0; it < jg; ++it) {          // full steps, mask-free
        __syncthreads();
        stageKV((it + 1) * 64, (it + 1) & 1);
        computeStep(it * 64, it & 1, false);
    }
    __syncthreads();
    computeStep(jg * 64, jg & 1, true);        // the one partial step

    // epilogue: reduce l, then write Y = O / l in PACKED layout
    for (int off = 1; off < 16; off <<= 1)
#pragma unroll
        for (int r = 0; r < 4; ++r) lsum[r] += __shfl_xor(lsum[r], off);
#pragma unroll
    for (int r = 0; r < 4; ++r) {
        float inv = 1.0f / lsum[r];
        size_t row = baseRow + q0 + quad * 4 + r;
#pragma unroll
        for (int nt = 0; nt < 4; ++nt) {
            int chunk = h * 2 + (nt >> 1);
            Y[((size_t)chunk * BT + row) * 32 + (nt & 1) * 16 + ln] =
                f2bf(o[nt][r] * inv);
        }
    }
}

extern "C" void kernel_launch(void* const* d_in, const int* in_sizes, int n_in,
                              void* d_out, int out_size, void* d_ws, size_t ws_size,
                              hipStream_t stream) {
    const float* x  = (const float*)d_in[0];
    const float* Wq = (const float*)d_in[1];
    const float* Wk = (const float*)d_in[2];
    const float* Wv = (const float*)d_in[3];
    const float* Wo = (const float*)d_in[4];
    float* out = (float*)d_out;

    char* ws = (char*)d_ws;
    // workspace (22.8 MB): slot0 is packed-x until qkv-gemm completes, then packed-y.
    unsigned short* xb  = (unsigned short*)(ws);                // packed x (8 MB)
    unsigned short* y   = (unsigned short*)(ws);                // alias: packed attn out
    unsigned short* wtq = (unsigned short*)(ws + 8388608);      // packed [Wq|Wk|Wv]
    unsigned short* wot = (unsigned short*)(ws + 10747904);     // packed Wo
    unsigned short* qkv = (unsigned short*)(ws + 12845056);     // 4096x1152 bf16 row-major
    unsigned short* Vt  = (unsigned short*)(ws + 22282240);     // 2x64x2048 bf16 (0.5 MB)

    hipLaunchKernelGGL(cast_pack_x_kernel, dim3(BT / 256, 32), dim3(256), 0, stream,
                       x, xb);
    hipLaunchKernelGGL(prep_w_kernel, dim3(DM / 256, 32, 4), dim3(256), 0, stream,
                       Wq, Wk, Wv, Wo, wtq, wot);

    // QKV = x @ [Wq|Wk|Wv] -> bf16 row-major; V cols also written transposed to Vt
    // 576 blocks = 8 XCDs x 4 row-strips x 18 cols (XCD-aware remap inside)
    hipLaunchKernelGGL(HIP_KERNEL_NAME(gemm_packed_kernel<LDQ>),
                       dim3((BT / 128) * (LDQ / 64)), dim3(256), 0, stream,
                       xb, wtq, (void*)qkv, Vt, 1, LDQ / 64);

    // flash attention (R0 4-wave) -> packed y (overwrites packed x, now dead)
    hipLaunchKernelGGL(attn_kernel, dim3(32 * 32), dim3(256), 0, stream,
                       qkv, Vt, y);

    // out = y @ Wo -> fp32; 512 blocks = 8 XCDs x 4 row-strips x 16 cols
    hipLaunchKernelGGL(HIP_KERNEL_NAME(gemm_packed_kernel<DM>),
                       dim3((BT / 128) * (DM / 64)), dim3(256), 0, stream,
                       y, wot, (void*)out, nullptr, 0, DM / 64);
}